// Round 1
// baseline (1683.342 us; speedup 1.0000x reference)
//
#include <hip/hip_runtime.h>
#include <math.h>

#define B_ 2
#define S_ 2048
#define D_ 1024
#define H_ 16
#define DEPTH_ 64
#define SCALE_ 0.125f   // 1/sqrt(64)

// ---------------------------------------------------------------------------
// Generic 64x64 tile fp32 GEMM pieces. Block = 256 threads (16x16 of 4x4).
// As/Bs stored [k][m] / [k][n], padded to 68 floats so rows stay 16B-aligned
// (float4 LDS reads) with <=2-way bank aliasing (free on CDNA4).
// ---------------------------------------------------------------------------

// C = X[M=4096,K=1024] @ W[1024,1024] + bias, written to head-split [B,H,S,64]
__global__ __launch_bounds__(256) void proj_kernel(
    const float* __restrict__ X, const float* __restrict__ W,
    const float* __restrict__ bias, float* __restrict__ out)
{
    __shared__ float As[16][68];
    __shared__ float Bs[16][68];
    const int tid = threadIdx.x;
    const int tx = tid & 15, ty = tid >> 4;
    const int m0 = blockIdx.y * 64;
    const int n0 = blockIdx.x * 64;
    float acc[4][4] = {};

    for (int kk = 0; kk < D_; kk += 16) {
        int idx = tid;
#pragma unroll
        for (int r = 0; r < 4; ++r, idx += 256) {
            int m = idx >> 4, k = idx & 15;
            As[k][m] = X[(size_t)(m0 + m) * D_ + kk + k];
        }
        idx = tid;
#pragma unroll
        for (int r = 0; r < 4; ++r, idx += 256) {
            int k = idx >> 6, n = idx & 63;
            Bs[k][n] = W[(size_t)(kk + k) * D_ + n0 + n];
        }
        __syncthreads();
#pragma unroll
        for (int k = 0; k < 16; ++k) {
            float4 a = *(const float4*)&As[k][ty * 4];
            float4 b = *(const float4*)&Bs[k][tx * 4];
            float av[4] = {a.x, a.y, a.z, a.w};
            float bv[4] = {b.x, b.y, b.z, b.w};
#pragma unroll
            for (int i = 0; i < 4; ++i)
#pragma unroll
                for (int j = 0; j < 4; ++j) acc[i][j] += av[i] * bv[j];
        }
        __syncthreads();
    }
#pragma unroll
    for (int i = 0; i < 4; ++i) {
        int m = m0 + ty * 4 + i;
        int b = m >> 11, s = m & 2047;
#pragma unroll
        for (int j = 0; j < 4; ++j) {
            int n = n0 + tx * 4 + j;
            int h = n >> 6, d = n & 63;
            out[((size_t)(b * H_ + h) * S_ + s) * DEPTH_ + d] = acc[i][j] + bias[n];
        }
    }
}

// logits[z, i, j] = scale * dot(qh[z,i,:], kh[z,j,:]) - 1e9*mask[b,j]
__global__ __launch_bounds__(256) void logits_kernel(
    const float* __restrict__ qh, const float* __restrict__ kh,
    const float* __restrict__ mask, float* __restrict__ attn)
{
    const int z = blockIdx.z;            // b*H + h
    const int b = z >> 4;
    const float* A  = qh + (size_t)z * S_ * DEPTH_;
    const float* Bm = kh + (size_t)z * S_ * DEPTH_;
    __shared__ float As[16][68];
    __shared__ float Bs[16][68];
    const int tid = threadIdx.x;
    const int tx = tid & 15, ty = tid >> 4;
    const int m0 = blockIdx.y * 64;
    const int n0 = blockIdx.x * 64;
    float acc[4][4] = {};

    for (int kk = 0; kk < DEPTH_; kk += 16) {
        int idx = tid;
#pragma unroll
        for (int r = 0; r < 4; ++r, idx += 256) {
            int m = idx >> 4, k = idx & 15;
            As[k][m] = A [(size_t)(m0 + m) * DEPTH_ + kk + k];
            Bs[k][m] = Bm[(size_t)(n0 + m) * DEPTH_ + kk + k];
        }
        __syncthreads();
#pragma unroll
        for (int k = 0; k < 16; ++k) {
            float4 a = *(const float4*)&As[k][ty * 4];
            float4 b4 = *(const float4*)&Bs[k][tx * 4];
            float av[4] = {a.x, a.y, a.z, a.w};
            float bv[4] = {b4.x, b4.y, b4.z, b4.w};
#pragma unroll
            for (int i = 0; i < 4; ++i)
#pragma unroll
                for (int j = 0; j < 4; ++j) acc[i][j] += av[i] * bv[j];
        }
        __syncthreads();
    }
    float* C = attn + (size_t)z * S_ * S_;
#pragma unroll
    for (int i = 0; i < 4; ++i) {
        int m = m0 + ty * 4 + i;
#pragma unroll
        for (int j = 0; j < 4; ++j) {
            int n = n0 + tx * 4 + j;
            float v = acc[i][j] * SCALE_ + mask[b * S_ + n] * (-1e9f);
            C[(size_t)m * S_ + n] = v;
        }
    }
}

// one block per row of 2048
__global__ __launch_bounds__(256) void softmax_kernel(float* __restrict__ attn)
{
    const size_t row = blockIdx.x;
    float4* p4 = (float4*)(attn + row * S_);
    const int tid = threadIdx.x;
    const int wave = tid >> 6, lane = tid & 63;
    __shared__ float redm[4];
    __shared__ float reds[4];

    float4 x0 = p4[tid];
    float4 x1 = p4[tid + 256];
    float m = fmaxf(fmaxf(fmaxf(x0.x, x0.y), fmaxf(x0.z, x0.w)),
                    fmaxf(fmaxf(x1.x, x1.y), fmaxf(x1.z, x1.w)));
#pragma unroll
    for (int off = 32; off; off >>= 1) m = fmaxf(m, __shfl_down(m, off, 64));
    if (lane == 0) redm[wave] = m;
    __syncthreads();
    m = fmaxf(fmaxf(redm[0], redm[1]), fmaxf(redm[2], redm[3]));

    x0.x = expf(x0.x - m); x0.y = expf(x0.y - m);
    x0.z = expf(x0.z - m); x0.w = expf(x0.w - m);
    x1.x = expf(x1.x - m); x1.y = expf(x1.y - m);
    x1.z = expf(x1.z - m); x1.w = expf(x1.w - m);
    float s = x0.x + x0.y + x0.z + x0.w + x1.x + x1.y + x1.z + x1.w;
#pragma unroll
    for (int off = 32; off; off >>= 1) s += __shfl_down(s, off, 64);
    if (lane == 0) reds[wave] = s;
    __syncthreads();
    s = reds[0] + reds[1] + reds[2] + reds[3];
    float inv = 1.0f / s;
    x0.x *= inv; x0.y *= inv; x0.z *= inv; x0.w *= inv;
    x1.x *= inv; x1.y *= inv; x1.z *= inv; x1.w *= inv;
    p4[tid] = x0;
    p4[tid + 256] = x1;
}

// ctx[z] = attn[z] (2048x2048) @ vh[z] (2048x64), written merged-head [B,S,D]
__global__ __launch_bounds__(256) void ctx_kernel(
    const float* __restrict__ attn, const float* __restrict__ vh,
    float* __restrict__ ctx)
{
    const int z = blockIdx.z;
    const int b = z >> 4, h = z & 15;
    const float* A = attn + (size_t)z * S_ * S_;
    const float* V = vh + (size_t)z * S_ * DEPTH_;
    __shared__ float As[16][68];
    __shared__ float Bs[16][68];
    const int tid = threadIdx.x;
    const int tx = tid & 15, ty = tid >> 4;
    const int m0 = blockIdx.y * 64;
    float acc[4][4] = {};

    for (int kk = 0; kk < S_; kk += 16) {
        int idx = tid;
#pragma unroll
        for (int r = 0; r < 4; ++r, idx += 256) {
            int m = idx >> 4, k = idx & 15;
            As[k][m] = A[(size_t)(m0 + m) * S_ + kk + k];
        }
        idx = tid;
#pragma unroll
        for (int r = 0; r < 4; ++r, idx += 256) {
            int k = idx >> 6, n = idx & 63;
            Bs[k][n] = V[(size_t)(kk + k) * DEPTH_ + n];
        }
        __syncthreads();
#pragma unroll
        for (int k = 0; k < 16; ++k) {
            float4 a = *(const float4*)&As[k][ty * 4];
            float4 b4 = *(const float4*)&Bs[k][tx * 4];
            float av[4] = {a.x, a.y, a.z, a.w};
            float bv[4] = {b4.x, b4.y, b4.z, b4.w};
#pragma unroll
            for (int i = 0; i < 4; ++i)
#pragma unroll
                for (int j = 0; j < 4; ++j) acc[i][j] += av[i] * bv[j];
        }
        __syncthreads();
    }
#pragma unroll
    for (int i = 0; i < 4; ++i) {
        int s = m0 + ty * 4 + i;
#pragma unroll
        for (int j = 0; j < 4; ++j) {
            int d = tx * 4 + j;
            ctx[((size_t)(b * S_ + s)) * D_ + h * DEPTH_ + d] = acc[i][j];
        }
    }
}

// out = ctx[4096,1024] @ Wo + bo, plain row-major
__global__ __launch_bounds__(256) void out_kernel(
    const float* __restrict__ X, const float* __restrict__ W,
    const float* __restrict__ bias, float* __restrict__ out)
{
    __shared__ float As[16][68];
    __shared__ float Bs[16][68];
    const int tid = threadIdx.x;
    const int tx = tid & 15, ty = tid >> 4;
    const int m0 = blockIdx.y * 64;
    const int n0 = blockIdx.x * 64;
    float acc[4][4] = {};

    for (int kk = 0; kk < D_; kk += 16) {
        int idx = tid;
#pragma unroll
        for (int r = 0; r < 4; ++r, idx += 256) {
            int m = idx >> 4, k = idx & 15;
            As[k][m] = X[(size_t)(m0 + m) * D_ + kk + k];
        }
        idx = tid;
#pragma unroll
        for (int r = 0; r < 4; ++r, idx += 256) {
            int k = idx >> 6, n = idx & 63;
            Bs[k][n] = W[(size_t)(kk + k) * D_ + n0 + n];
        }
        __syncthreads();
#pragma unroll
        for (int k = 0; k < 16; ++k) {
            float4 a = *(const float4*)&As[k][ty * 4];
            float4 b4 = *(const float4*)&Bs[k][tx * 4];
            float av[4] = {a.x, a.y, a.z, a.w};
            float bv[4] = {b4.x, b4.y, b4.z, b4.w};
#pragma unroll
            for (int i = 0; i < 4; ++i)
#pragma unroll
                for (int j = 0; j < 4; ++j) acc[i][j] += av[i] * bv[j];
        }
        __syncthreads();
    }
#pragma unroll
    for (int i = 0; i < 4; ++i) {
        int m = m0 + ty * 4 + i;
#pragma unroll
        for (int j = 0; j < 4; ++j) {
            int n = n0 + tx * 4 + j;
            out[(size_t)m * D_ + n] = acc[i][j] + bias[n];
        }
    }
}

extern "C" void kernel_launch(void* const* d_in, const int* in_sizes, int n_in,
                              void* d_out, int out_size, void* d_ws, size_t ws_size,
                              hipStream_t stream)
{
    const float* q    = (const float*)d_in[0];
    const float* k    = (const float*)d_in[1];
    const float* v    = (const float*)d_in[2];
    const float* mask = (const float*)d_in[3];
    const float* Wq   = (const float*)d_in[4];
    const float* bq   = (const float*)d_in[5];
    const float* Wk   = (const float*)d_in[6];
    const float* bk   = (const float*)d_in[7];
    const float* Wv   = (const float*)d_in[8];
    const float* bv   = (const float*)d_in[9];
    const float* Wo   = (const float*)d_in[10];
    const float* bo   = (const float*)d_in[11];

    float* out  = (float*)d_out;
    float* attn = out + (size_t)B_ * S_ * D_;   // second output

    float* ws  = (float*)d_ws;
    float* qh  = ws;                                  // [B,H,S,64]
    float* kh  = qh + (size_t)B_ * S_ * D_;
    float* vh  = kh + (size_t)B_ * S_ * D_;
    float* ctx = vh + (size_t)B_ * S_ * D_;           // [B,S,D]

    dim3 blk(256);
    dim3 gproj(D_ / 64, (B_ * S_) / 64);              // (16, 64)
    proj_kernel<<<gproj, blk, 0, stream>>>(q, Wq, bq, qh);
    proj_kernel<<<gproj, blk, 0, stream>>>(k, Wk, bk, kh);
    proj_kernel<<<gproj, blk, 0, stream>>>(v, Wv, bv, vh);

    dim3 glog(S_ / 64, S_ / 64, B_ * H_);             // (32, 32, 32)
    logits_kernel<<<glog, blk, 0, stream>>>(qh, kh, mask, attn);

    softmax_kernel<<<dim3(B_ * H_ * S_), blk, 0, stream>>>(attn);

    dim3 gctx(1, S_ / 64, B_ * H_);                   // (1, 32, 32)
    ctx_kernel<<<gctx, blk, 0, stream>>>(attn, vh, ctx);

    dim3 gout(D_ / 64, (B_ * S_) / 64);
    out_kernel<<<gout, blk, 0, stream>>>(ctx, Wo, bo, out);
}